// Round 2
// baseline (137.660 us; speedup 1.0000x reference)
//
#include <hip/hip_runtime.h>
#include <math.h>

#define NG   512
#define NPER 256
#define DD   128
#define EPER 4096
#define KK   128
#define NT   1024
#define NW   16     // waves per block

// Dynamic LDS carve (bytes):
//   sX4     [256][32] float4   131072   (x staged once; P5 reads from here)
//   sScore4 [64] float4          1024
//   sGF     [256] float2         2048
//   sPoolS  [16][128] float      8192
//   sPoolM  [16][128] float      8192
//   sR2     [128] float2         1024
//   sDeg    [256] int            1024
//   sRank   [256] int            1024
//   sXWn    [256] float          1024
//   sDinv   [256] float          1024
#define SMEM_BYTES 155648

// One block (16 waves) per graph, 1 block/CU (152KB LDS). x is read from
// global EXACTLY ONCE: regs -> ds_write (write forces materialization, so the
// compiler cannot rematerialize the global load for P5 the way it provably
// did in the 2-pass version: VGPR_Count=32 < |q|). P1 dots from regs, P5
// pools from LDS. 16-lane groups sweep contiguous 256B row segments in LDS
// -> canonical conflict-free b128 pattern, no swizzle needed.
__global__ __launch_bounds__(NT, 4) void sag_fused(
    const float* __restrict__ x,      // [N, 128] f32
    const int*   __restrict__ esrc,   // [E]
    const int*   __restrict__ edst,   // [E]
    const float* __restrict__ gcn_w,  // [128]
    const float* __restrict__ gcn_b,  // [1]
    const float* __restrict__ lin_w,  // [256, 128]
    const float* __restrict__ lin_b,  // [128]
    float* __restrict__ out)          // [512, 128]
{
  const int g    = blockIdx.x;
  const int tid  = threadIdx.x;
  const int lane = tid & 63;
  const int wave = tid >> 6;           // 0..15
  const int j    = lane & 15;          // dim-group within 16-lane group
  const int sub  = lane >> 4;          // 0..3
  const int slot = wave * 4 + sub;     // 0..63: node-slot

  extern __shared__ __align__(16) char smem[];
  float4* sX4     = (float4*)(smem);
  float4* sScore4 = (float4*)(smem + 131072);
  float2* sGF     = (float2*)(smem + 132096);
  float*  sPoolS  = (float*)(smem + 134144);   // [NW][DD]
  float*  sPoolM  = (float*)(smem + 142336);   // [NW][DD]
  float2* sR2     = (float2*)(smem + 150528);  // [DD]
  int*    sDeg    = (int*)(smem + 151552);
  int*    sRank   = (int*)(smem + 152576);
  float*  sXWn    = (float*)(smem + 153600);
  float*  sDinv   = (float*)(smem + 154624);
  float*  sScore  = (float*)sScore4;
  float*  sR      = (float*)sR2;

  // ---- Front-load ALL global reads: 2 int4 edges + 8 float4 x + 2 float4 w
  const int4* es4 = (const int4*)(esrc + (size_t)g * EPER);
  const int4* ed4 = (const int4*)(edst + (size_t)g * EPER);
  int4 sa = es4[tid];                  // 1024 threads x 4 edges = 4096 edges
  int4 da = ed4[tid];

  const float4* xg4 = (const float4*)(x + (size_t)g * NPER * DD);
  const int colbase = slot * 32 + j;   // per-thread x base (float4 units)
  float4 q0[4], q1[4];
  #pragma unroll
  for (int r = 0; r < 4; ++r) {
    q0[r] = xg4[r * 2048 + colbase];          // node r*64+slot, dims [4j,4j+4)
    q1[r] = xg4[r * 2048 + colbase + 16];     // dims [64+4j, 64+4j+4)
  }
  float4 wa = ((const float4*)gcn_w)[j];
  float4 wb = ((const float4*)gcn_w)[16 + j];

  if (tid < NPER) { sDeg[tid] = 1; sRank[tid] = 0; }
  __syncthreads();                                      // B1

  // ---- Degree (needs only edges)
  atomicAdd(&sDeg[da.x & 255], 1);
  atomicAdd(&sDeg[da.y & 255], 1);
  atomicAdd(&sDeg[da.z & 255], 1);
  atomicAdd(&sDeg[da.w & 255], 1);

  // ---- P1: stage x to LDS + xw dot from registers
  #pragma unroll
  for (int r = 0; r < 4; ++r) {
    sX4[r * 2048 + colbase]      = q0[r];     // linear copy, conflict-free
    sX4[r * 2048 + colbase + 16] = q1[r];
    float acc = q0[r].x*wa.x + q0[r].y*wa.y + q0[r].z*wa.z + q0[r].w*wa.w
              + q1[r].x*wb.x + q1[r].y*wb.y + q1[r].z*wb.z + q1[r].w*wb.w;
    acc += __shfl_xor(acc, 1);          // DPP within 16-lane group
    acc += __shfl_xor(acc, 2);
    acc += __shfl_xor(acc, 4);
    acc += __shfl_xor(acc, 8);
    if (j == 0) sXWn[r * 64 + slot] = acc;    // raw xw
  }
  __syncthreads();                                      // B2

  if (tid < NPER) {
    float dv = 1.0f / sqrtf((float)sDeg[tid]);
    float xw = sXWn[tid];
    sDinv[tid]  = dv;
    sXWn[tid]   = xw * dv;              // pre-scaled (same-thread overwrite: safe)
    sScore[tid] = xw * dv * dv;         // self-loop term
  }
  __syncthreads();                                      // B3

  // ---- P3: score[dst] += xwn[src] * dinv[dst]
  {
    int s0 = sa.x & 255, d0 = da.x & 255;
    int s1 = sa.y & 255, d1 = da.y & 255;
    int s2 = sa.z & 255, d2 = da.z & 255;
    int s3 = sa.w & 255, d3 = da.w & 255;
    atomicAdd(&sScore[d0], sXWn[s0] * sDinv[d0]);
    atomicAdd(&sScore[d1], sXWn[s1] * sDinv[d1]);
    atomicAdd(&sScore[d2], sXWn[s2] * sDinv[d2]);
    atomicAdd(&sScore[d3], sXWn[s3] * sDinv[d3]);
  }
  __syncthreads();                                      // B4

  // ---- P4: stable top-K rank (4 threads/node, b128 broadcast reads)
  {
    int node = tid & 255;
    int seg  = tid >> 8;                // 0..3
    float s_i = sScore[node];
    int base = seg * 16;
    int part = 0;
    #pragma unroll 8
    for (int t = 0; t < 16; ++t) {
      float4 v = sScore4[base + t];
      int jj = (base + t) * 4;
      part += (v.x > s_i) || (v.x == s_i && (jj + 0) < node);
      part += (v.y > s_i) || (v.y == s_i && (jj + 1) < node);
      part += (v.z > s_i) || (v.z == s_i && (jj + 2) < node);
      part += (v.w > s_i) || (v.w == s_i && (jj + 3) < node);
    }
    atomicAdd(&sRank[node], part);
  }
  __syncthreads();                                      // B5

  if (tid < NPER) {
    bool kp = sRank[tid] < KK;          // ranks are a permutation of 0..255
    float gate = tanhf(sScore[tid] + gcn_b[0]);
    sGF[tid] = make_float2(kp ? gate : 0.0f, kp ? 0.0f : INFINITY);
  }
  __syncthreads();                                      // B6

  // ---- P5: gated mean/max pool, x from LDS (no second global read)
  float su0=0,su1=0,su2=0,su3=0,su4=0,su5=0,su6=0,su7=0;
  float mx0=-INFINITY,mx1=-INFINITY,mx2=-INFINITY,mx3=-INFINITY;
  float mx4=-INFINITY,mx5=-INFINITY,mx6=-INFINITY,mx7=-INFINITY;
  #pragma unroll
  for (int r = 0; r < 4; ++r) {
    float2 gf = sGF[r * 64 + slot];     // 4 addr/wave, conflict-free broadcast
    float4 v0 = sX4[r * 2048 + colbase];        // contiguous 256B per 16 lanes
    float4 v1 = sX4[r * 2048 + colbase + 16];
    float g1 = gf.x, fb = gf.y;
    float a;
    a = v0.x * g1; su0 += a; mx0 = fmaxf(mx0, a - fb);
    a = v0.y * g1; su1 += a; mx1 = fmaxf(mx1, a - fb);
    a = v0.z * g1; su2 += a; mx2 = fmaxf(mx2, a - fb);
    a = v0.w * g1; su3 += a; mx3 = fmaxf(mx3, a - fb);
    a = v1.x * g1; su4 += a; mx4 = fmaxf(mx4, a - fb);
    a = v1.y * g1; su5 += a; mx5 = fmaxf(mx5, a - fb);
    a = v1.z * g1; su6 += a; mx6 = fmaxf(mx6, a - fb);
    a = v1.w * g1; su7 += a; mx7 = fmaxf(mx7, a - fb);
  }
  // reduce over sub (lanes j, j^16, j^32, j^48)
  #define RED_S(v) v += __shfl_xor(v,16); v += __shfl_xor(v,32);
  #define RED_M(v) v = fmaxf(v,__shfl_xor(v,16)); v = fmaxf(v,__shfl_xor(v,32));
  RED_S(su0) RED_S(su1) RED_S(su2) RED_S(su3)
  RED_S(su4) RED_S(su5) RED_S(su6) RED_S(su7)
  RED_M(mx0) RED_M(mx1) RED_M(mx2) RED_M(mx3)
  RED_M(mx4) RED_M(mx5) RED_M(mx6) RED_M(mx7)
  if (sub == 0) {
    ((float4*)&sPoolS[wave * DD + 4 * j])[0]      = make_float4(su0, su1, su2, su3);
    ((float4*)&sPoolS[wave * DD + 64 + 4 * j])[0] = make_float4(su4, su5, su6, su7);
    ((float4*)&sPoolM[wave * DD + 4 * j])[0]      = make_float4(mx0, mx1, mx2, mx3);
    ((float4*)&sPoolM[wave * DD + 64 + 4 * j])[0] = make_float4(mx4, mx5, mx6, mx7);
  }
  __syncthreads();                                      // B7

  if (tid < DD) {                       // mean dims
    float s = 0.f;
    #pragma unroll
    for (int w = 0; w < NW; ++w) s += sPoolS[w * DD + tid];
    sR[tid] = s * (1.0f / KK);
  } else if (tid < 2 * DD) {            // max dims
    int d = tid - DD;
    float m = -INFINITY;
    #pragma unroll
    for (int w = 0; w < NW; ++w) m = fmaxf(m, sPoolM[w * DD + d]);
    sR[tid] = m;
  }
  __syncthreads();                                      // B8

  // ---- P6: out = [mean||max] @ lin_w + lin_b (lin_w L2-hot across 512 blocks)
  const float2* lw2 = (const float2*)lin_w;
  float a0 = 0.f, a1 = 0.f;
  #pragma unroll
  for (int t = 0; t < 8; ++t) {
    int k2 = wave * 8 + t;
    float2 rv = sR2[k2];                       // readout[2k2], readout[2k2+1]
    float2 p0 = lw2[(2 * k2) * 64 + lane];
    float2 p1 = lw2[(2 * k2 + 1) * 64 + lane];
    a0 += rv.x * p0.x + rv.y * p1.x;
    a1 += rv.x * p0.y + rv.y * p1.y;
  }
  float2* sP2 = (float2*)sPoolS;               // reuse as matvec partials (16*64 float2 = 8KB)
  sP2[wave * 64 + lane] = make_float2(a0, a1); // safe: all waves passed B8
  __syncthreads();                                      // B9
  if (wave == 0) {
    float2 a = sP2[lane];
    #pragma unroll
    for (int w = 1; w < NW; ++w) { float2 p = sP2[w * 64 + lane]; a.x += p.x; a.y += p.y; }
    float2 bb = ((const float2*)lin_b)[lane];
    a.x += bb.x; a.y += bb.y;
    ((float2*)out)[(size_t)g * 64 + lane] = a;
  }
}

extern "C" void kernel_launch(void* const* d_in, const int* in_sizes, int n_in,
                              void* d_out, int out_size, void* d_ws, size_t ws_size,
                              hipStream_t stream) {
  static bool s_init = false;
  if (!s_init) {
    (void)hipFuncSetAttribute((const void*)sag_fused,
                              hipFuncAttributeMaxDynamicSharedMemorySize, SMEM_BYTES);
    s_init = true;
  }
  const float* x  = (const float*)d_in[0];
  // d_in[1] = graph_indicator (unused: equal-size contiguous graphs)
  const int*   ei = (const int*)d_in[2];
  const float* gw = (const float*)d_in[3];
  const float* gb = (const float*)d_in[4];
  const float* lw = (const float*)d_in[5];
  const float* lb = (const float*)d_in[6];
  float* out = (float*)d_out;
  const int E = in_sizes[2] / 2;       // edge_index is [2, E]
  sag_fused<<<NG, NT, SMEM_BYTES, stream>>>(x, ei, ei + E, gw, gb, lw, lb, out);
}

// Round 4
// 118.744 us; speedup vs baseline: 1.1593x; 1.1593x over previous
//
#include <hip/hip_runtime.h>
#include <math.h>

#define NG   512
#define NPER 256
#define DD   128
#define EPER 4096
#define KK   128
#define NT   1024
#define NW   16     // waves per block

// Fixed-point scale for the LDS score accumulation. Edge terms |t| <~ 6,
// deg <~ 48 -> |sum| < 512 -> |sum * 2^22| < 2^31 (no overflow).
// Quantization ~2.4e-7/term, rms over ~17 terms ~5e-7 — same order as the
// existing float-atomic reordering noise; absmax headroom is ~10x.
#define SFX_SCALE 4194304.0f            // 2^22
#define SFX_INV   2.384185791015625e-07f // 2^-22

// R1 structure (1024 thr, 2 blocks/CU). Single change vs R1: P3's
// atomicAdd(float) -> atomicAdd(int) fixed point. Theory: LDS float
// atomicAdd lowers to a CAS retry loop; at ~16-way per-address contention
// (4096 edges -> 256 nodes) the retry storm is the invariant ~30µs that
// R0/R1/R2 all share. Int atomics are native ds_add_u32 (pipelined).
__global__ __launch_bounds__(NT, 8) void sag_fused(
    const float* __restrict__ x,      // [N, 128] f32
    const int*   __restrict__ esrc,   // [E]
    const int*   __restrict__ edst,   // [E]
    const float* __restrict__ gcn_w,  // [128]
    const float* __restrict__ gcn_b,  // [1]
    const float* __restrict__ lin_w,  // [256, 128]
    const float* __restrict__ lin_b,  // [128]
    float* __restrict__ out)          // [512, 128]
{
  const int g    = blockIdx.x;
  const int tid  = threadIdx.x;
  const int lane = tid & 63;
  const int wave = tid >> 6;           // 0..15
  const int j    = lane & 15;          // dim-group within 16-lane group
  const int sub  = lane >> 4;          // 0..3
  const int slot = wave * 4 + sub;     // 0..63: node-slot

  __shared__ int    sDeg[NPER];
  __shared__ int    sRank[NPER];
  __shared__ int    sFx[NPER];         // fixed-point edge-term accumulator
  __shared__ float  sXWn[NPER];        // raw xw, then xw*dinv*SCALE after B2
  __shared__ float  sDinv[NPER];
  __shared__ float4 sScore4[NPER / 4];
  __shared__ float2 sGF[NPER];         // (gate_or_0, 0_or_inf)
  __shared__ float  sPoolS[NW][DD];    // per-wave pool partials (reused for matvec)
  __shared__ float  sPoolM[NW][DD];
  __shared__ float2 sR2[DD];           // readout: [0..127]=mean, [128..255]=max (as pairs)
  float* sScore = (float*)sScore4;
  float* sR     = (float*)sR2;

  // ---- Front-load ALL global reads: 2 int4 edges + 8 float4 x + 2 float4 w
  const int4* es4 = (const int4*)(esrc + (size_t)g * EPER);
  const int4* ed4 = (const int4*)(edst + (size_t)g * EPER);
  int4 sa = es4[tid];                  // 1024 threads x 4 edges = 4096 edges
  int4 da = ed4[tid];

  const float4* xg4 = (const float4*)(x + (size_t)g * NPER * DD);
  const int colbase = slot * 32 + j;   // per-thread x base (float4 units)
  float4 q0[4], q1[4];
  #pragma unroll
  for (int r = 0; r < 4; ++r) {
    q0[r] = xg4[r * 2048 + colbase];          // node r*64+slot, dims [4j,4j+4)
    q1[r] = xg4[r * 2048 + colbase + 16];     // dims [64+4j, 64+4j+4)
  }
  float4 wa = ((const float4*)gcn_w)[j];
  float4 wb = ((const float4*)gcn_w)[16 + j];

  if (tid < NPER) { sDeg[tid] = 1; sRank[tid] = 0; sFx[tid] = 0; }
  __syncthreads();                                      // B1

  // ---- Degree (needs only edges) — native ds_add_u32
  atomicAdd(&sDeg[da.x & 255], 1);
  atomicAdd(&sDeg[da.y & 255], 1);
  atomicAdd(&sDeg[da.z & 255], 1);
  atomicAdd(&sDeg[da.w & 255], 1);

  // ---- P1: xw dot from registers (independent of degree)
  #pragma unroll
  for (int r = 0; r < 4; ++r) {
    float acc = q0[r].x*wa.x + q0[r].y*wa.y + q0[r].z*wa.z + q0[r].w*wa.w
              + q1[r].x*wb.x + q1[r].y*wb.y + q1[r].z*wb.z + q1[r].w*wb.w;
    acc += __shfl_xor(acc, 1);          // DPP within 16-lane group
    acc += __shfl_xor(acc, 2);
    acc += __shfl_xor(acc, 4);
    acc += __shfl_xor(acc, 8);
    if (j == 0) sXWn[r * 64 + slot] = acc;    // raw xw
  }
  __syncthreads();                                      // B2

  if (tid < NPER) {
    float dv = 1.0f / sqrtf((float)sDeg[tid]);
    float xw = sXWn[tid];
    sDinv[tid]  = dv;
    sXWn[tid]   = xw * dv * SFX_SCALE;  // pre-scaled for fixed-point edge terms
    sScore[tid] = xw * dv * dv;         // self-loop term (float)
  }
  __syncthreads();                                      // B3

  // ---- P3: scoreFx[dst] += round(xwn[src] * dinv[dst] * 2^22)  (native int atomics)
  {
    int s0 = sa.x & 255, d0 = da.x & 255;
    int s1 = sa.y & 255, d1 = da.y & 255;
    int s2 = sa.z & 255, d2 = da.z & 255;
    int s3 = sa.w & 255, d3 = da.w & 255;
    atomicAdd(&sFx[d0], __float2int_rn(sXWn[s0] * sDinv[d0]));
    atomicAdd(&sFx[d1], __float2int_rn(sXWn[s1] * sDinv[d1]));
    atomicAdd(&sFx[d2], __float2int_rn(sXWn[s2] * sDinv[d2]));
    atomicAdd(&sFx[d3], __float2int_rn(sXWn[s3] * sDinv[d3]));
  }
  __syncthreads();                                      // B4

  // ---- finalize score in float
  if (tid < NPER) sScore[tid] += (float)sFx[tid] * SFX_INV;
  __syncthreads();                                      // B4b

  // ---- P4: stable top-K rank (4 threads/node, b128 broadcast reads)
  {
    int node = tid & 255;
    int seg  = tid >> 8;                // 0..3
    float s_i = sScore[node];
    int base = seg * 16;
    int part = 0;
    #pragma unroll 8
    for (int t = 0; t < 16; ++t) {
      float4 v = sScore4[base + t];
      int jj = (base + t) * 4;
      part += (v.x > s_i) || (v.x == s_i && (jj + 0) < node);
      part += (v.y > s_i) || (v.y == s_i && (jj + 1) < node);
      part += (v.z > s_i) || (v.z == s_i && (jj + 2) < node);
      part += (v.w > s_i) || (v.w == s_i && (jj + 3) < node);
    }
    atomicAdd(&sRank[node], part);
  }
  __syncthreads();                                      // B5

  if (tid < NPER) {
    bool kp = sRank[tid] < KK;          // ranks are a permutation of 0..255
    float gate = tanhf(sScore[tid] + gcn_b[0]);
    sGF[tid] = make_float2(kp ? gate : 0.0f, kp ? 0.0f : INFINITY);
  }
  __syncthreads();                                      // B6

  // ---- P5: gated mean/max pool from registers (no global loads)
  float su0=0,su1=0,su2=0,su3=0,su4=0,su5=0,su6=0,su7=0;
  float mx0=-INFINITY,mx1=-INFINITY,mx2=-INFINITY,mx3=-INFINITY;
  float mx4=-INFINITY,mx5=-INFINITY,mx6=-INFINITY,mx7=-INFINITY;
  #pragma unroll
  for (int r = 0; r < 4; ++r) {
    float2 gf = sGF[r * 64 + slot];     // 4 addr/wave, conflict-free broadcast
    float g1 = gf.x, fb = gf.y;
    float a;
    a = q0[r].x * g1; su0 += a; mx0 = fmaxf(mx0, a - fb);
    a = q0[r].y * g1; su1 += a; mx1 = fmaxf(mx1, a - fb);
    a = q0[r].z * g1; su2 += a; mx2 = fmaxf(mx2, a - fb);
    a = q0[r].w * g1; su3 += a; mx3 = fmaxf(mx3, a - fb);
    a = q1[r].x * g1; su4 += a; mx4 = fmaxf(mx4, a - fb);
    a = q1[r].y * g1; su5 += a; mx5 = fmaxf(mx5, a - fb);
    a = q1[r].z * g1; su6 += a; mx6 = fmaxf(mx6, a - fb);
    a = q1[r].w * g1; su7 += a; mx7 = fmaxf(mx7, a - fb);
  }
  // reduce over sub (lanes j, j^16, j^32, j^48)
  #define RED_S(v) v += __shfl_xor(v,16); v += __shfl_xor(v,32);
  #define RED_M(v) v = fmaxf(v,__shfl_xor(v,16)); v = fmaxf(v,__shfl_xor(v,32));
  RED_S(su0) RED_S(su1) RED_S(su2) RED_S(su3)
  RED_S(su4) RED_S(su5) RED_S(su6) RED_S(su7)
  RED_M(mx0) RED_M(mx1) RED_M(mx2) RED_M(mx3)
  RED_M(mx4) RED_M(mx5) RED_M(mx6) RED_M(mx7)
  if (sub == 0) {
    ((float4*)&sPoolS[wave][4 * j])[0]      = make_float4(su0, su1, su2, su3);
    ((float4*)&sPoolS[wave][64 + 4 * j])[0] = make_float4(su4, su5, su6, su7);
    ((float4*)&sPoolM[wave][4 * j])[0]      = make_float4(mx0, mx1, mx2, mx3);
    ((float4*)&sPoolM[wave][64 + 4 * j])[0] = make_float4(mx4, mx5, mx6, mx7);
  }
  __syncthreads();                                      // B7

  if (tid < DD) {                       // mean dims
    float s = 0.f;
    #pragma unroll
    for (int w = 0; w < NW; ++w) s += sPoolS[w][tid];
    sR[tid] = s * (1.0f / KK);
  } else if (tid < 2 * DD) {            // max dims
    int d = tid - DD;
    float m = -INFINITY;
    #pragma unroll
    for (int w = 0; w < NW; ++w) m = fmaxf(m, sPoolM[w][d]);
    sR[tid] = m;
  }
  __syncthreads();                                      // B8

  // ---- P6: out = [mean||max] @ lin_w + lin_b (lin_w L2-hot across 512 blocks)
  const float2* lw2 = (const float2*)lin_w;
  float a0 = 0.f, a1 = 0.f;
  #pragma unroll
  for (int t = 0; t < 8; ++t) {
    int k2 = wave * 8 + t;
    float2 rv = sR2[k2];                       // readout[2k2], readout[2k2+1]
    float2 p0 = lw2[(2 * k2) * 64 + lane];
    float2 p1 = lw2[(2 * k2 + 1) * 64 + lane];
    a0 += rv.x * p0.x + rv.y * p1.x;
    a1 += rv.x * p0.y + rv.y * p1.y;
  }
  float2* sP2 = (float2*)sPoolS;               // reuse as matvec partials (16*64 float2 = 8KB)
  sP2[wave * 64 + lane] = make_float2(a0, a1); // safe: all waves passed B8
  __syncthreads();                                      // B9
  if (wave == 0) {
    float2 a = sP2[lane];
    #pragma unroll
    for (int w = 1; w < NW; ++w) { float2 p = sP2[w * 64 + lane]; a.x += p.x; a.y += p.y; }
    float2 bb = ((const float2*)lin_b)[lane];
    a.x += bb.x; a.y += bb.y;
    ((float2*)out)[(size_t)g * 64 + lane] = a;
  }
}

extern "C" void kernel_launch(void* const* d_in, const int* in_sizes, int n_in,
                              void* d_out, int out_size, void* d_ws, size_t ws_size,
                              hipStream_t stream) {
  const float* x  = (const float*)d_in[0];
  // d_in[1] = graph_indicator (unused: equal-size contiguous graphs)
  const int*   ei = (const int*)d_in[2];
  const float* gw = (const float*)d_in[3];
  const float* gb = (const float*)d_in[4];
  const float* lw = (const float*)d_in[5];
  const float* lb = (const float*)d_in[6];
  float* out = (float*)d_out;
  const int E = in_sizes[2] / 2;       // edge_index is [2, E]
  sag_fused<<<NG, NT, 0, stream>>>(x, ei, ei + E, gw, gb, lw, lb, out);
}